// Round 4
// baseline (1164.100 us; speedup 1.0000x reference)
//
#include <hip/hip_runtime.h>
#include <cstdint>
#include <cstddef>

// ---------------------------------------------------------------------------
// VirtualNodeGNN: 3x GENConv(softmax aggr) + virtual node + mean pool.
// R4 changes vs R3 (1085 us):
//   - ln512 pass ELIMINATED: gemm1 epilogue accumulates per-row (sum,sum^2)
//     (shfl-reduce + atomics into 800KB rstat), k_rowfin -> (rstd, -mu*rstd),
//     gemm2 applies LN+ReLU while staging A into LDS (g/b in LDS).
//   - h kept as PRE-vn-broadcast state: gemm2 epilogue adds vn[batch[row]]
//     (layers 2,3) + residual; ln256 no longer writes h back (saves 204 MB).
//   - dataflow: h_l = h_{l-1} + vn_{l-1}[batch] + conv_l; vnsum reads h_l;
//     LN reads h_l + vn_l[batch]. Matches reference exactly.
// ---------------------------------------------------------------------------

typedef _Float16 half8_t __attribute__((ext_vector_type(8)));
typedef _Float16 half4_t __attribute__((ext_vector_type(4)));
typedef float    floatx4 __attribute__((ext_vector_type(4)));

#define DEVINL __device__ __forceinline__

DEVINL float wave_sum(float v) {
#pragma unroll
  for (int m = 32; m; m >>= 1) v += __shfl_xor(v, m, 64);
  return v;
}

// ------------------------------- node encoder ------------------------------
__global__ __launch_bounds__(256) void k_node_enc(
    const float* __restrict__ x, const float* __restrict__ W,
    const float* __restrict__ bias, float* __restrict__ h, int Nr) {
  __shared__ float sW[9 * 256];
  __shared__ float sb[256];
  __shared__ float sx[72];
  const int j = threadIdx.x;
#pragma unroll
  for (int k = 0; k < 9; ++k) sW[k * 256 + j] = W[k * 256 + j];
  sb[j] = bias[j];
  const int row0 = blockIdx.x * 8;
  if (j < 72) {
    int p = row0 * 9 + j;
    sx[j] = (p < Nr * 9) ? x[p] : 0.f;
  }
  __syncthreads();
  for (int r = 0; r < 8; ++r) {
    int row = row0 + r;
    if (row >= Nr) break;
    float acc = sb[j];
#pragma unroll
    for (int k = 0; k < 9; ++k) acc = fmaf(sx[r * 9 + k], sW[k * 256 + j], acc);
    h[(size_t)row * 256 + j] = acc;
  }
}

// ------------------------- counting / scan / CSR ---------------------------
__global__ void k_count(const int* __restrict__ batch, int* __restrict__ counts, int n) {
  int i = blockIdx.x * 256 + threadIdx.x;
  if (i < n) atomicAdd(&counts[batch[i]], 1);
}

__global__ void k_deg(const int* __restrict__ ei, int* __restrict__ deg, int E_) {
  int e = blockIdx.x * 256 + threadIdx.x;
  if (e < E_) atomicAdd(&deg[ei[E_ + e]], 1);  // row 1 of edge_index = dst
}

__global__ __launch_bounds__(256) void k_scan1(
    const int* __restrict__ in, int* __restrict__ out1, int* __restrict__ bsum, int n) {
  __shared__ int tmp[256];
  const int t = threadIdx.x;
  const int base = blockIdx.x * 1024;
  int v[4];
  int run = 0;
#pragma unroll
  for (int i = 0; i < 4; ++i) {
    int p = base + t * 4 + i;
    int xv = (p < n) ? in[p] : 0;
    run += xv;
    v[i] = run;
  }
  tmp[t] = run;
  __syncthreads();
  for (int off = 1; off < 256; off <<= 1) {
    int u = (t >= off) ? tmp[t - off] : 0;
    __syncthreads();
    tmp[t] += u;
    __syncthreads();
  }
  int excl = tmp[t] - run;
#pragma unroll
  for (int i = 0; i < 4; ++i) {
    int p = base + t * 4 + i;
    if (p < n) out1[p] = v[i] + excl;
  }
  if (t == 255) bsum[blockIdx.x] = tmp[255];
}

__global__ void k_scan2(int* bsum, int nb, int* ptr0) {
  if (threadIdx.x == 0 && blockIdx.x == 0) {
    int run = 0;
    for (int i = 0; i < nb; ++i) { int xv = bsum[i]; bsum[i] = run; run += xv; }
    ptr0[0] = 0;
  }
}

__global__ __launch_bounds__(256) void k_scan3(int* out1, const int* __restrict__ bsum, int n) {
  int add = bsum[blockIdx.x];
  int p0 = blockIdx.x * 1024 + threadIdx.x * 4;
#pragma unroll
  for (int i = 0; i < 4; ++i) {
    int p = p0 + i;
    if (p < n) out1[p] += add;
  }
}

__global__ void k_copy(const int* __restrict__ a, int* __restrict__ b, int n) {
  int i = blockIdx.x * 256 + threadIdx.x;
  if (i < n) b[i] = a[i];
}

__global__ void k_csrfill(const int* __restrict__ ei, int* __restrict__ cursor,
                          int* __restrict__ csr_src, int* __restrict__ csr_eid, int E_) {
  int e = blockIdx.x * 256 + threadIdx.x;
  if (e < E_) {
    int d = ei[E_ + e];
    int pos = atomicAdd(&cursor[d], 1);
    csr_src[pos] = ei[e];
    csr_eid[pos] = e;
  }
}

__global__ void k_invc(const int* __restrict__ counts, float* __restrict__ invc, int Bn) {
  int i = blockIdx.x * 256 + threadIdx.x;
  if (i < Bn) {
    int c = counts[i];
    invc[i] = 1.f / (float)(c > 1 ? c : 1);
  }
}

__global__ void k_vninit(const float* __restrict__ emb, float* __restrict__ vn) {
  vn[(size_t)blockIdx.x * 256 + threadIdx.x] = emb[threadIdx.x];
}

// ------------------------------ LayerNorm 256 ------------------------------
// wave-per-row. VN: logical input = h + vn[batch[row]] (h not written back).
template <int VN>
__global__ __launch_bounds__(256) void k_ln256(
    const float* __restrict__ h, const float* __restrict__ vn,
    const int* __restrict__ batch, const float* __restrict__ g,
    const float* __restrict__ b, _Float16* __restrict__ out, int Nr) {
  int row = blockIdx.x * 4 + (threadIdx.x >> 6);
  if (row >= Nr) return;
  int lane = threadIdx.x & 63;
  float4 xv = *(const float4*)(h + (size_t)row * 256 + lane * 4);
  if constexpr (VN) {
    int bb = batch[row];
    float4 vv = *(const float4*)(vn + (size_t)bb * 256 + lane * 4);
    xv.x += vv.x; xv.y += vv.y; xv.z += vv.z; xv.w += vv.w;
  }
  float s = wave_sum(xv.x + xv.y + xv.z + xv.w);
  float mu = s * (1.f / 256.f);
  float d0 = xv.x - mu, d1 = xv.y - mu, d2 = xv.z - mu, d3 = xv.w - mu;
  float v = wave_sum(d0 * d0 + d1 * d1 + d2 * d2 + d3 * d3);
  float rstd = rsqrtf(v * (1.f / 256.f) + 1e-5f);
  float4 gv = *(const float4*)(g + lane * 4);
  float4 bv = *(const float4*)(b + lane * 4);
  half4_t o;
  o[0] = (_Float16)fmaxf(d0 * rstd * gv.x + bv.x, 0.f);
  o[1] = (_Float16)fmaxf(d1 * rstd * gv.y + bv.y, 0.f);
  o[2] = (_Float16)fmaxf(d2 * rstd * gv.z + bv.z, 0.f);
  o[3] = (_Float16)fmaxf(d3 * rstd * gv.w + bv.w, 0.f);
  *(half4_t*)(out + (size_t)row * 256 + lane * 4) = o;
}

// --------------------------- softmax aggregation ---------------------------
__global__ __launch_bounds__(256) void k_aggregate(
    const _Float16* __restrict__ hn, const float* __restrict__ eattr,
    const float* __restrict__ edgeW, const float* __restrict__ edgeB,
    const int* __restrict__ indptr, const int* __restrict__ csr_src,
    const int* __restrict__ csr_eid, const float* __restrict__ tptr,
    _Float16* __restrict__ agg, int Nr) {
  __shared__ float sW[4 * 256];  // [k*256+j] k=0..2 weights, k=3 bias
  const int tj = threadIdx.x;
  sW[tj] = edgeW[tj];
  sW[256 + tj] = edgeW[256 + tj];
  sW[512 + tj] = edgeW[512 + tj];
  sW[768 + tj] = edgeB[tj];
  __syncthreads();

  int node = blockIdx.x * 4 + (threadIdx.x >> 6);
  if (node >= Nr) return;
  int lane = threadIdx.x & 63;
  float tval = tptr[0];
  int e0 = indptr[node], e1 = indptr[node + 1];
  float M[4], D[4], Nu[4];
#pragma unroll
  for (int i = 0; i < 4; ++i) { M[i] = -1e38f; D[i] = 0.f; Nu[i] = 0.f; }
  for (int s = e0; s < e1; ++s) {
    int srcn = csr_src[s];
    int eid = csr_eid[s];
    float ex0 = eattr[(size_t)eid * 3 + 0];
    float ex1 = eattr[(size_t)eid * 3 + 1];
    float ex2 = eattr[(size_t)eid * 3 + 2];
    half4_t hv = *(const half4_t*)(hn + (size_t)srcn * 256 + lane * 4);
#pragma unroll
    for (int i = 0; i < 4; ++i) {
      int j = lane * 4 + i;
      float eaj = fmaf(ex0, sW[j], fmaf(ex1, sW[256 + j], fmaf(ex2, sW[512 + j], sW[768 + j])));
      float msg = fmaxf((float)hv[i] + eaj, 0.f) + 1e-7f;
      float sc = msg * tval;
      float nM = fmaxf(M[i], sc);
      float sOld = __expf(M[i] - nM);
      float pr = __expf(sc - nM);
      D[i] = D[i] * sOld + pr;
      Nu[i] = Nu[i] * sOld + pr * msg;
      M[i] = nM;
    }
  }
  half4_t hs = *(const half4_t*)(hn + (size_t)node * 256 + lane * 4);
  half4_t res;
#pragma unroll
  for (int i = 0; i < 4; ++i)
    res[i] = (_Float16)(Nu[i] / (D[i] + 1e-16f) + (float)hs[i]);
  *(half4_t*)(agg + (size_t)node * 256 + lane * 4) = res;
}

// ------------------------------- GEMM1 -------------------------------------
// t1[M,512] = agg[M,256] @ W1 + b1 (f16 out), plus per-row (sum,sum^2) into
// rstat via 16-lane shfl-reduce + atomics (8 atomic pairs per row total).
__global__ __launch_bounds__(256, 2) void k_gemm1(
    const _Float16* __restrict__ A, const _Float16* __restrict__ BT,
    const float* __restrict__ bias, _Float16* __restrict__ outh,
    float2* __restrict__ rstat, int M) {
  constexpr int K = 256, NN = 512;
  __shared__ _Float16 ldsA[128 * 64];
  __shared__ _Float16 ldsB[128 * 64];
  const int lane = threadIdx.x & 63;
  const int wv = threadIdx.x >> 6;
  const int m0 = blockIdx.x * 128;
  const int n0 = blockIdx.y * 128;
  const int wm = (wv >> 1) * 64;
  const int wn = (wv & 1) * 64;
  const int q = lane >> 4;
  const int l16 = lane & 15;
  floatx4 acc[4][4] = {};

  size_t offA[4], offB[4];
  int ldsOff[4];
#pragma unroll
  for (int i = 0; i < 4; ++i) {
    int p = (i * 4 + wv) * 64 + lane;
    int r = p >> 3;
    int s = p & 7;
    int g = s ^ (r & 7);
    int rowA = m0 + r;
    rowA = rowA < M ? rowA : (M - 1);
    offA[i] = (size_t)rowA * K + g * 8;
    offB[i] = (size_t)(n0 + r) * K + g * 8;
    ldsOff[i] = p * 8;
  }
  half8_t ra[4], rb[4];
  auto loadtile = [&](int kt) {
#pragma unroll
    for (int i = 0; i < 4; ++i) {
      ra[i] = *(const half8_t*)(A + offA[i] + kt);
      rb[i] = *(const half8_t*)(BT + offB[i] + kt);
    }
  };
  auto writetile = [&]() {
#pragma unroll
    for (int i = 0; i < 4; ++i) {
      *(half8_t*)(ldsA + ldsOff[i]) = ra[i];
      *(half8_t*)(ldsB + ldsOff[i]) = rb[i];
    }
  };

  loadtile(0);
  writetile();
  for (int kt = 0; kt < K; kt += 64) {
    __syncthreads();
    if (kt + 64 < K) loadtile(kt + 64);
#pragma unroll
    for (int kk = 0; kk < 2; ++kk) {
      half8_t af[4], bf[4];
      const int c8 = kk * 4 + q;
#pragma unroll
      for (int rt = 0; rt < 4; ++rt) {
        int r = wm + rt * 16 + l16;
        af[rt] = *(const half8_t*)(ldsA + (size_t)(r * 8 + (c8 ^ (r & 7))) * 8);
      }
#pragma unroll
      for (int ct = 0; ct < 4; ++ct) {
        int n = wn + ct * 16 + l16;
        bf[ct] = *(const half8_t*)(ldsB + (size_t)(n * 8 + (c8 ^ (n & 7))) * 8);
      }
#pragma unroll
      for (int rt = 0; rt < 4; ++rt)
#pragma unroll
        for (int ct = 0; ct < 4; ++ct)
          acc[rt][ct] = __builtin_amdgcn_mfma_f32_16x16x32_f16(af[rt], bf[ct], acc[rt][ct], 0, 0, 0);
    }
    __syncthreads();
    if (kt + 64 < K) writetile();
  }

#pragma unroll
  for (int rt = 0; rt < 4; ++rt) {
#pragma unroll
    for (int rr = 0; rr < 4; ++rr) {
      int row = m0 + wm + rt * 16 + q * 4 + rr;  // C/D: col=lane&15, row=q*4+reg
      float vv[4];
      float s = 0.f, s2 = 0.f;
#pragma unroll
      for (int ct = 0; ct < 4; ++ct) {
        int col = n0 + wn + ct * 16 + l16;
        float v = acc[rt][ct][rr] + bias[col];
        vv[ct] = v;
        s += v;
        s2 += v * v;
      }
      // reduce over the 16 col-lanes of this row
#pragma unroll
      for (int m = 1; m < 16; m <<= 1) {
        s += __shfl_xor(s, m, 64);
        s2 += __shfl_xor(s2, m, 64);
      }
      if (row < M) {
#pragma unroll
        for (int ct = 0; ct < 4; ++ct) {
          int col = n0 + wn + ct * 16 + l16;
          outh[(size_t)row * NN + col] = (_Float16)vv[ct];
        }
        if (l16 == 0) {
          atomicAdd(&rstat[row].x, s);
          atomicAdd(&rstat[row].y, s2);
        }
      }
    }
  }
}

// rstat: (sum, sum^2) -> (a=rstd, c=-mu*rstd)
__global__ void k_rowfin(float2* rstat, int n) {
  int i = blockIdx.x * 256 + threadIdx.x;
  if (i < n) {
    float2 st = rstat[i];
    float mu = st.x * (1.f / 512.f);
    float var = st.y * (1.f / 512.f) - mu * mu;
    float rs = rsqrtf(var + 1e-5f);
    rstat[i] = make_float2(rs, -mu * rs);
  }
}

// ------------------------------- GEMM2 -------------------------------------
// h[M,256] += LN_relu(t1)[M,512] @ W2 + b2 (+ vn[batch[row]] if VN).
// LN+ReLU applied on the fly while staging A into LDS (g/b in LDS, per-row
// (a,c) coeffs preloaded once per thread-chunk).
template <int VN>
__global__ __launch_bounds__(256, 2) void k_gemm2(
    const _Float16* __restrict__ A, const _Float16* __restrict__ BT,
    const float* __restrict__ bias, const float2* __restrict__ rstat,
    const float* __restrict__ lg, const float* __restrict__ lb,
    const float* __restrict__ vn, const int* __restrict__ batch,
    float* __restrict__ outf, int M) {
  constexpr int K = 512, NN = 256;
  __shared__ _Float16 ldsA[128 * 64];
  __shared__ _Float16 ldsB[128 * 64];
  __shared__ float sg[512];
  __shared__ float sbt[512];
  const int tid = threadIdx.x;
  sg[tid] = lg[tid];
  sg[tid + 256] = lg[tid + 256];
  sbt[tid] = lb[tid];
  sbt[tid + 256] = lb[tid + 256];
  __syncthreads();  // sg/sbt visible before any staging uses them

  const int lane = tid & 63;
  const int wv = tid >> 6;
  const int m0 = blockIdx.x * 128;
  const int n0 = blockIdx.y * 128;
  const int wm = (wv >> 1) * 64;
  const int wn = (wv & 1) * 64;
  const int q = lane >> 4;
  const int l16 = lane & 15;
  floatx4 acc[4][4] = {};

  size_t offA[4], offB[4];
  int ldsOff[4], gcol[4];
  float aco[4], cco[4];
#pragma unroll
  for (int i = 0; i < 4; ++i) {
    int p = (i * 4 + wv) * 64 + lane;
    int r = p >> 3;
    int s = p & 7;
    int g = s ^ (r & 7);
    int rowA = m0 + r;
    rowA = rowA < M ? rowA : (M - 1);
    offA[i] = (size_t)rowA * K + g * 8;
    offB[i] = (size_t)(n0 + r) * K + g * 8;
    ldsOff[i] = p * 8;
    gcol[i] = g * 8;
    float2 st = rstat[rowA];  // row fixed across k-tiles
    aco[i] = st.x;
    cco[i] = st.y;
  }
  half8_t ra[4], rb[4];
  auto loadtile = [&](int kt) {
#pragma unroll
    for (int i = 0; i < 4; ++i) {
      half8_t xa = *(const half8_t*)(A + offA[i] + kt);
      rb[i] = *(const half8_t*)(BT + offB[i] + kt);
      int c0 = kt + gcol[i];
      half8_t ya;
#pragma unroll
      for (int j = 0; j < 8; ++j) {
        float e = fmaf((float)xa[j], aco[i], cco[i]);
        float y = fmaf(e, sg[c0 + j], sbt[c0 + j]);
        ya[j] = (_Float16)fmaxf(y, 0.f);
      }
      ra[i] = ya;
    }
  };
  auto writetile = [&]() {
#pragma unroll
    for (int i = 0; i < 4; ++i) {
      *(half8_t*)(ldsA + ldsOff[i]) = ra[i];
      *(half8_t*)(ldsB + ldsOff[i]) = rb[i];
    }
  };

  loadtile(0);
  writetile();
  for (int kt = 0; kt < K; kt += 64) {
    __syncthreads();
    if (kt + 64 < K) loadtile(kt + 64);
#pragma unroll
    for (int kk = 0; kk < 2; ++kk) {
      half8_t af[4], bf[4];
      const int c8 = kk * 4 + q;
#pragma unroll
      for (int rt = 0; rt < 4; ++rt) {
        int r = wm + rt * 16 + l16;
        af[rt] = *(const half8_t*)(ldsA + (size_t)(r * 8 + (c8 ^ (r & 7))) * 8);
      }
#pragma unroll
      for (int ct = 0; ct < 4; ++ct) {
        int n = wn + ct * 16 + l16;
        bf[ct] = *(const half8_t*)(ldsB + (size_t)(n * 8 + (c8 ^ (n & 7))) * 8);
      }
#pragma unroll
      for (int rt = 0; rt < 4; ++rt)
#pragma unroll
        for (int ct = 0; ct < 4; ++ct)
          acc[rt][ct] = __builtin_amdgcn_mfma_f32_16x16x32_f16(af[rt], bf[ct], acc[rt][ct], 0, 0, 0);
    }
    __syncthreads();
    if (kt + 64 < K) writetile();
  }

#pragma unroll
  for (int rt = 0; rt < 4; ++rt) {
#pragma unroll
    for (int rr = 0; rr < 4; ++rr) {
      int row = m0 + wm + rt * 16 + q * 4 + rr;
      if (row < M) {
        int bb = 0;
        if constexpr (VN) bb = batch[row];
#pragma unroll
        for (int ct = 0; ct < 4; ++ct) {
          int col = n0 + wn + ct * 16 + l16;
          float v = acc[rt][ct][rr] + bias[col];
          if constexpr (VN) v += vn[(size_t)bb * 256 + col];
          outf[(size_t)row * NN + col] += v;
        }
      }
    }
  }
}

// ---------------------- weight transpose+convert to f16 --------------------
__global__ __launch_bounds__(256) void k_wcvt(
    const float* __restrict__ W, _Float16* __restrict__ WT, int K_, int N_) {
  int idx = blockIdx.x * 256 + threadIdx.x;
  if (idx < K_ * N_) {
    int k = idx / N_, n = idx - k * N_;
    WT[(size_t)n * K_ + k] = (_Float16)W[idx];
  }
}

// --------------------------- virtual node sum ------------------------------
__global__ __launch_bounds__(256) void k_vnsum(
    const float* __restrict__ h, float* __restrict__ vn,
    const int* __restrict__ bptr, const float* __restrict__ invc) {
  int b = blockIdx.x, j = threadIdx.x;
  int n0 = bptr[b], n1 = bptr[b + 1];
  float acc = 0.f;
  for (int n = n0; n < n1; ++n) acc += h[(size_t)n * 256 + j];
  vn[(size_t)b * 256 + j] += acc * invc[b];
}

__global__ __launch_bounds__(256) void k_pool_f16(
    const _Float16* __restrict__ hnf, const int* __restrict__ bptr,
    const float* __restrict__ invc, float* __restrict__ out) {
  int b = blockIdx.x, j = threadIdx.x;
  int n0 = bptr[b], n1 = bptr[b + 1];
  float acc = 0.f;
  for (int n = n0; n < n1; ++n) acc += (float)hnf[(size_t)n * 256 + j];
  out[(size_t)b * 256 + j] = acc * invc[b];
}

// ---------------------------------------------------------------------------
extern "C" void kernel_launch(void* const* d_in, const int* in_sizes, int n_in,
                              void* d_out, int out_size, void* d_ws, size_t ws_size,
                              hipStream_t stream) {
  const float* x      = (const float*)d_in[0];
  const int*   ei     = (const int*)d_in[1];
  const float* eattr  = (const float*)d_in[2];
  const int*   batch  = (const int*)d_in[3];
  const float* nodeW  = (const float*)d_in[4];
  const float* nodeB  = (const float*)d_in[5];
  const float* edgeW  = (const float*)d_in[6];
  const float* edgeB  = (const float*)d_in[7];
  const float* vnemb  = (const float*)d_in[8];
  const float* lng    = (const float*)d_in[9];
  const float* lnb    = (const float*)d_in[10];
  const float* tparam = (const float*)d_in[11];
  const float* W1     = (const float*)d_in[12];
  const float* b1     = (const float*)d_in[13];
  const float* mlng   = (const float*)d_in[14];
  const float* mlnb   = (const float*)d_in[15];
  const float* W2     = (const float*)d_in[16];
  const float* b2     = (const float*)d_in[17];
  float* out = (float*)d_out;

  const int N = in_sizes[3];         // 100000
  const int E = in_sizes[1] / 2;     // 200000
  const int B = out_size / 256;      // 2048

  char* p = (char*)d_ws;
  auto take = [&](size_t bytes) -> char* {
    char* r = p;
    p += (bytes + 255) & ~(size_t)255;
    return r;
  };
  float*     h   = (float*)take((size_t)N * 256 * 4);
  _Float16*  t1  = (_Float16*)take((size_t)N * 512 * 2);  // GEMM1 out [N,512]
  _Float16*  hn  = t1;                 // [N,256] f16 aliases t1 (disjoint lifetimes)
  _Float16*  agg = (_Float16*)take((size_t)N * 256 * 2);
  _Float16*  W1T = (_Float16*)take((size_t)3 * 512 * 256 * 2);
  _Float16*  W2T = (_Float16*)take((size_t)3 * 256 * 512 * 2);
  float2*    rstat = (float2*)take((size_t)N * 8);
  float*     vn  = (float*)take((size_t)B * 256 * 4);
  int*       counts = (int*)take((size_t)B * 4);
  int*       bptr   = (int*)take((size_t)(B + 1) * 4);
  float*     invc   = (float*)take((size_t)B * 4);
  int*       deg    = (int*)take((size_t)N * 4);
  int*       indptr = (int*)take((size_t)(N + 1) * 4);
  int*       cursor = (int*)take((size_t)N * 4);
  int*       csr_src = (int*)take((size_t)E * 4);
  int*       csr_eid = (int*)take((size_t)E * 4);
  int*       bsum    = (int*)take(512 * 4);
  (void)ws_size; (void)n_in;

  hipMemsetAsync(counts, 0, (size_t)B * 4, stream);
  hipMemsetAsync(deg, 0, (size_t)N * 4, stream);

  k_node_enc<<<(N + 7) / 8, 256, 0, stream>>>(x, nodeW, nodeB, h, N);

  const int nbB = (B + 1023) / 1024;
  k_count<<<(N + 255) / 256, 256, 0, stream>>>(batch, counts, N);
  k_scan1<<<nbB, 256, 0, stream>>>(counts, bptr + 1, bsum, B);
  k_scan2<<<1, 64, 0, stream>>>(bsum, nbB, bptr);
  k_scan3<<<nbB, 256, 0, stream>>>(bptr + 1, bsum, B);
  k_invc<<<(B + 255) / 256, 256, 0, stream>>>(counts, invc, B);

  const int nbN = (N + 1023) / 1024;
  k_deg<<<(E + 255) / 256, 256, 0, stream>>>(ei, deg, E);
  k_scan1<<<nbN, 256, 0, stream>>>(deg, indptr + 1, bsum, N);
  k_scan2<<<1, 64, 0, stream>>>(bsum, nbN, indptr);
  k_scan3<<<nbN, 256, 0, stream>>>(indptr + 1, bsum, N);
  k_copy<<<(N + 255) / 256, 256, 0, stream>>>(indptr, cursor, N);
  k_csrfill<<<(E + 255) / 256, 256, 0, stream>>>(ei, cursor, csr_src, csr_eid, E);

  for (int l = 0; l < 3; ++l) {
    k_wcvt<<<512, 256, 0, stream>>>(W1 + (size_t)l * 256 * 512, W1T + (size_t)l * 512 * 256, 256, 512);
    k_wcvt<<<512, 256, 0, stream>>>(W2 + (size_t)l * 512 * 256, W2T + (size_t)l * 256 * 512, 512, 256);
  }
  k_vninit<<<B, 256, 0, stream>>>(vnemb, vn);

  const int lnGrid = (N + 3) / 4;
  const int mTiles = (N + 127) / 128;
  for (int l = 1; l <= 3; ++l) {
    if (l == 1)
      k_ln256<0><<<lnGrid, 256, 0, stream>>>(
          h, nullptr, nullptr, lng + (size_t)l * 256, lnb + (size_t)l * 256, hn, N);
    else
      k_ln256<1><<<lnGrid, 256, 0, stream>>>(
          h, vn, batch, lng + (size_t)l * 256, lnb + (size_t)l * 256, hn, N);
    k_aggregate<<<lnGrid, 256, 0, stream>>>(hn, eattr, edgeW, edgeB, indptr, csr_src, csr_eid,
                                            tparam + (l - 1), agg, N);
    hipMemsetAsync(rstat, 0, (size_t)N * 8, stream);
    k_gemm1<<<dim3(mTiles, 4), 256, 0, stream>>>(
        agg, W1T + (size_t)(l - 1) * 512 * 256, b1 + (size_t)(l - 1) * 512, t1, rstat, N);
    k_rowfin<<<(N + 255) / 256, 256, 0, stream>>>(rstat, N);
    if (l == 1)
      k_gemm2<0><<<dim3(mTiles, 2), 256, 0, stream>>>(
          t1, W2T + (size_t)(l - 1) * 256 * 512, b2 + (size_t)(l - 1) * 256, rstat,
          mlng + (size_t)(l - 1) * 512, mlnb + (size_t)(l - 1) * 512, nullptr, nullptr, h, N);
    else
      k_gemm2<1><<<dim3(mTiles, 2), 256, 0, stream>>>(
          t1, W2T + (size_t)(l - 1) * 256 * 512, b2 + (size_t)(l - 1) * 256, rstat,
          mlng + (size_t)(l - 1) * 512, mlnb + (size_t)(l - 1) * 512, vn, batch, h, N);
    k_vnsum<<<B, 256, 0, stream>>>(h, vn, bptr, invc);
  }

  // final: logical h = h + vn3[batch], LN -> f16, mean pool
  k_ln256<1><<<lnGrid, 256, 0, stream>>>(h, vn, batch, lng, lnb, hn, N);
  k_pool_f16<<<B, 256, 0, stream>>>(hn, bptr, invc, out);
}

// Round 5
// 1040.555 us; speedup vs baseline: 1.1187x; 1.1187x over previous
//
#include <hip/hip_runtime.h>
#include <cstdint>
#include <cstddef>

// ---------------------------------------------------------------------------
// VirtualNodeGNN: 3x GENConv(softmax aggr) + virtual node + mean pool.
// R5 = R4 with the GEMM2 pipeline bug fixed:
//   R4 put LN math inside loadtile -> dependent VALU forced the vmcnt wait
//   BEFORE the MFMA block (MfmaUtil 14->7.3%, 70->138us). R5 keeps loadtile
//   as pure raw loads; LN+ReLU applied in writetile (post-compute, where the
//   vmcnt drain belongs). Fusions kept: no ln512 pass, no h write-back in
//   ln256, vn[batch] added in gemm2 epilogue.
// ---------------------------------------------------------------------------

typedef _Float16 half8_t __attribute__((ext_vector_type(8)));
typedef _Float16 half4_t __attribute__((ext_vector_type(4)));
typedef float    floatx4 __attribute__((ext_vector_type(4)));

#define DEVINL __device__ __forceinline__

DEVINL float wave_sum(float v) {
#pragma unroll
  for (int m = 32; m; m >>= 1) v += __shfl_xor(v, m, 64);
  return v;
}

// ------------------------------- node encoder ------------------------------
__global__ __launch_bounds__(256) void k_node_enc(
    const float* __restrict__ x, const float* __restrict__ W,
    const float* __restrict__ bias, float* __restrict__ h, int Nr) {
  __shared__ float sW[9 * 256];
  __shared__ float sb[256];
  __shared__ float sx[72];
  const int j = threadIdx.x;
#pragma unroll
  for (int k = 0; k < 9; ++k) sW[k * 256 + j] = W[k * 256 + j];
  sb[j] = bias[j];
  const int row0 = blockIdx.x * 8;
  if (j < 72) {
    int p = row0 * 9 + j;
    sx[j] = (p < Nr * 9) ? x[p] : 0.f;
  }
  __syncthreads();
  for (int r = 0; r < 8; ++r) {
    int row = row0 + r;
    if (row >= Nr) break;
    float acc = sb[j];
#pragma unroll
    for (int k = 0; k < 9; ++k) acc = fmaf(sx[r * 9 + k], sW[k * 256 + j], acc);
    h[(size_t)row * 256 + j] = acc;
  }
}

// ------------------------- counting / scan / CSR ---------------------------
__global__ void k_count(const int* __restrict__ batch, int* __restrict__ counts, int n) {
  int i = blockIdx.x * 256 + threadIdx.x;
  if (i < n) atomicAdd(&counts[batch[i]], 1);
}

__global__ void k_deg(const int* __restrict__ ei, int* __restrict__ deg, int E_) {
  int e = blockIdx.x * 256 + threadIdx.x;
  if (e < E_) atomicAdd(&deg[ei[E_ + e]], 1);  // row 1 of edge_index = dst
}

__global__ __launch_bounds__(256) void k_scan1(
    const int* __restrict__ in, int* __restrict__ out1, int* __restrict__ bsum, int n) {
  __shared__ int tmp[256];
  const int t = threadIdx.x;
  const int base = blockIdx.x * 1024;
  int v[4];
  int run = 0;
#pragma unroll
  for (int i = 0; i < 4; ++i) {
    int p = base + t * 4 + i;
    int xv = (p < n) ? in[p] : 0;
    run += xv;
    v[i] = run;
  }
  tmp[t] = run;
  __syncthreads();
  for (int off = 1; off < 256; off <<= 1) {
    int u = (t >= off) ? tmp[t - off] : 0;
    __syncthreads();
    tmp[t] += u;
    __syncthreads();
  }
  int excl = tmp[t] - run;
#pragma unroll
  for (int i = 0; i < 4; ++i) {
    int p = base + t * 4 + i;
    if (p < n) out1[p] = v[i] + excl;
  }
  if (t == 255) bsum[blockIdx.x] = tmp[255];
}

__global__ void k_scan2(int* bsum, int nb, int* ptr0) {
  if (threadIdx.x == 0 && blockIdx.x == 0) {
    int run = 0;
    for (int i = 0; i < nb; ++i) { int xv = bsum[i]; bsum[i] = run; run += xv; }
    ptr0[0] = 0;
  }
}

__global__ __launch_bounds__(256) void k_scan3(int* out1, const int* __restrict__ bsum, int n) {
  int add = bsum[blockIdx.x];
  int p0 = blockIdx.x * 1024 + threadIdx.x * 4;
#pragma unroll
  for (int i = 0; i < 4; ++i) {
    int p = p0 + i;
    if (p < n) out1[p] += add;
  }
}

__global__ void k_copy(const int* __restrict__ a, int* __restrict__ b, int n) {
  int i = blockIdx.x * 256 + threadIdx.x;
  if (i < n) b[i] = a[i];
}

__global__ void k_csrfill(const int* __restrict__ ei, int* __restrict__ cursor,
                          int* __restrict__ csr_src, int* __restrict__ csr_eid, int E_) {
  int e = blockIdx.x * 256 + threadIdx.x;
  if (e < E_) {
    int d = ei[E_ + e];
    int pos = atomicAdd(&cursor[d], 1);
    csr_src[pos] = ei[e];
    csr_eid[pos] = e;
  }
}

__global__ void k_invc(const int* __restrict__ counts, float* __restrict__ invc, int Bn) {
  int i = blockIdx.x * 256 + threadIdx.x;
  if (i < Bn) {
    int c = counts[i];
    invc[i] = 1.f / (float)(c > 1 ? c : 1);
  }
}

__global__ void k_vninit(const float* __restrict__ emb, float* __restrict__ vn) {
  vn[(size_t)blockIdx.x * 256 + threadIdx.x] = emb[threadIdx.x];
}

// ------------------------------ LayerNorm 256 ------------------------------
// wave-per-row. VN: logical input = h + vn[batch[row]] (h not written back).
template <int VN>
__global__ __launch_bounds__(256) void k_ln256(
    const float* __restrict__ h, const float* __restrict__ vn,
    const int* __restrict__ batch, const float* __restrict__ g,
    const float* __restrict__ b, _Float16* __restrict__ out, int Nr) {
  int row = blockIdx.x * 4 + (threadIdx.x >> 6);
  if (row >= Nr) return;
  int lane = threadIdx.x & 63;
  float4 xv = *(const float4*)(h + (size_t)row * 256 + lane * 4);
  if constexpr (VN) {
    int bb = batch[row];
    float4 vv = *(const float4*)(vn + (size_t)bb * 256 + lane * 4);
    xv.x += vv.x; xv.y += vv.y; xv.z += vv.z; xv.w += vv.w;
  }
  float s = wave_sum(xv.x + xv.y + xv.z + xv.w);
  float mu = s * (1.f / 256.f);
  float d0 = xv.x - mu, d1 = xv.y - mu, d2 = xv.z - mu, d3 = xv.w - mu;
  float v = wave_sum(d0 * d0 + d1 * d1 + d2 * d2 + d3 * d3);
  float rstd = rsqrtf(v * (1.f / 256.f) + 1e-5f);
  float4 gv = *(const float4*)(g + lane * 4);
  float4 bv = *(const float4*)(b + lane * 4);
  half4_t o;
  o[0] = (_Float16)fmaxf(d0 * rstd * gv.x + bv.x, 0.f);
  o[1] = (_Float16)fmaxf(d1 * rstd * gv.y + bv.y, 0.f);
  o[2] = (_Float16)fmaxf(d2 * rstd * gv.z + bv.z, 0.f);
  o[3] = (_Float16)fmaxf(d3 * rstd * gv.w + bv.w, 0.f);
  *(half4_t*)(out + (size_t)row * 256 + lane * 4) = o;
}

// --------------------------- softmax aggregation ---------------------------
__global__ __launch_bounds__(256) void k_aggregate(
    const _Float16* __restrict__ hn, const float* __restrict__ eattr,
    const float* __restrict__ edgeW, const float* __restrict__ edgeB,
    const int* __restrict__ indptr, const int* __restrict__ csr_src,
    const int* __restrict__ csr_eid, const float* __restrict__ tptr,
    _Float16* __restrict__ agg, int Nr) {
  __shared__ float sW[4 * 256];  // [k*256+j] k=0..2 weights, k=3 bias
  const int tj = threadIdx.x;
  sW[tj] = edgeW[tj];
  sW[256 + tj] = edgeW[256 + tj];
  sW[512 + tj] = edgeW[512 + tj];
  sW[768 + tj] = edgeB[tj];
  __syncthreads();

  int node = blockIdx.x * 4 + (threadIdx.x >> 6);
  if (node >= Nr) return;
  int lane = threadIdx.x & 63;
  float tval = tptr[0];
  int e0 = indptr[node], e1 = indptr[node + 1];
  float M[4], D[4], Nu[4];
#pragma unroll
  for (int i = 0; i < 4; ++i) { M[i] = -1e38f; D[i] = 0.f; Nu[i] = 0.f; }
  for (int s = e0; s < e1; ++s) {
    int srcn = csr_src[s];
    int eid = csr_eid[s];
    float ex0 = eattr[(size_t)eid * 3 + 0];
    float ex1 = eattr[(size_t)eid * 3 + 1];
    float ex2 = eattr[(size_t)eid * 3 + 2];
    half4_t hv = *(const half4_t*)(hn + (size_t)srcn * 256 + lane * 4);
#pragma unroll
    for (int i = 0; i < 4; ++i) {
      int j = lane * 4 + i;
      float eaj = fmaf(ex0, sW[j], fmaf(ex1, sW[256 + j], fmaf(ex2, sW[512 + j], sW[768 + j])));
      float msg = fmaxf((float)hv[i] + eaj, 0.f) + 1e-7f;
      float sc = msg * tval;
      float nM = fmaxf(M[i], sc);
      float sOld = __expf(M[i] - nM);
      float pr = __expf(sc - nM);
      D[i] = D[i] * sOld + pr;
      Nu[i] = Nu[i] * sOld + pr * msg;
      M[i] = nM;
    }
  }
  half4_t hs = *(const half4_t*)(hn + (size_t)node * 256 + lane * 4);
  half4_t res;
#pragma unroll
  for (int i = 0; i < 4; ++i)
    res[i] = (_Float16)(Nu[i] / (D[i] + 1e-16f) + (float)hs[i]);
  *(half4_t*)(agg + (size_t)node * 256 + lane * 4) = res;
}

// ------------------------------- GEMM1 -------------------------------------
// t1[M,512] = agg[M,256] @ W1 + b1 (f16 out), plus per-row (sum,sum^2) into
// rstat via 16-lane shfl-reduce + atomics.
__global__ __launch_bounds__(256, 2) void k_gemm1(
    const _Float16* __restrict__ A, const _Float16* __restrict__ BT,
    const float* __restrict__ bias, _Float16* __restrict__ outh,
    float2* __restrict__ rstat, int M) {
  constexpr int K = 256, NN = 512;
  __shared__ _Float16 ldsA[128 * 64];
  __shared__ _Float16 ldsB[128 * 64];
  const int lane = threadIdx.x & 63;
  const int wv = threadIdx.x >> 6;
  const int m0 = blockIdx.x * 128;
  const int n0 = blockIdx.y * 128;
  const int wm = (wv >> 1) * 64;
  const int wn = (wv & 1) * 64;
  const int q = lane >> 4;
  const int l16 = lane & 15;
  floatx4 acc[4][4] = {};

  size_t offA[4], offB[4];
  int ldsOff[4];
#pragma unroll
  for (int i = 0; i < 4; ++i) {
    int p = (i * 4 + wv) * 64 + lane;
    int r = p >> 3;
    int s = p & 7;
    int g = s ^ (r & 7);
    int rowA = m0 + r;
    rowA = rowA < M ? rowA : (M - 1);
    offA[i] = (size_t)rowA * K + g * 8;
    offB[i] = (size_t)(n0 + r) * K + g * 8;
    ldsOff[i] = p * 8;
  }
  half8_t ra[4], rb[4];
  auto loadtile = [&](int kt) {
#pragma unroll
    for (int i = 0; i < 4; ++i) {
      ra[i] = *(const half8_t*)(A + offA[i] + kt);
      rb[i] = *(const half8_t*)(BT + offB[i] + kt);
    }
  };
  auto writetile = [&]() {
#pragma unroll
    for (int i = 0; i < 4; ++i) {
      *(half8_t*)(ldsA + ldsOff[i]) = ra[i];
      *(half8_t*)(ldsB + ldsOff[i]) = rb[i];
    }
  };

  loadtile(0);
  writetile();
  for (int kt = 0; kt < K; kt += 64) {
    __syncthreads();
    if (kt + 64 < K) loadtile(kt + 64);
#pragma unroll
    for (int kk = 0; kk < 2; ++kk) {
      half8_t af[4], bf[4];
      const int c8 = kk * 4 + q;
#pragma unroll
      for (int rt = 0; rt < 4; ++rt) {
        int r = wm + rt * 16 + l16;
        af[rt] = *(const half8_t*)(ldsA + (size_t)(r * 8 + (c8 ^ (r & 7))) * 8);
      }
#pragma unroll
      for (int ct = 0; ct < 4; ++ct) {
        int n = wn + ct * 16 + l16;
        bf[ct] = *(const half8_t*)(ldsB + (size_t)(n * 8 + (c8 ^ (n & 7))) * 8);
      }
#pragma unroll
      for (int rt = 0; rt < 4; ++rt)
#pragma unroll
        for (int ct = 0; ct < 4; ++ct)
          acc[rt][ct] = __builtin_amdgcn_mfma_f32_16x16x32_f16(af[rt], bf[ct], acc[rt][ct], 0, 0, 0);
    }
    __syncthreads();
    if (kt + 64 < K) writetile();
  }

#pragma unroll
  for (int rt = 0; rt < 4; ++rt) {
#pragma unroll
    for (int rr = 0; rr < 4; ++rr) {
      int row = m0 + wm + rt * 16 + q * 4 + rr;  // C/D: col=lane&15, row=q*4+reg
      float vv[4];
      float s = 0.f, s2 = 0.f;
#pragma unroll
      for (int ct = 0; ct < 4; ++ct) {
        int col = n0 + wn + ct * 16 + l16;
        float v = acc[rt][ct][rr] + bias[col];
        vv[ct] = v;
        s += v;
        s2 += v * v;
      }
#pragma unroll
      for (int m = 1; m < 16; m <<= 1) {
        s += __shfl_xor(s, m, 64);
        s2 += __shfl_xor(s2, m, 64);
      }
      if (row < M) {
#pragma unroll
        for (int ct = 0; ct < 4; ++ct) {
          int col = n0 + wn + ct * 16 + l16;
          outh[(size_t)row * NN + col] = (_Float16)vv[ct];
        }
        if (l16 == 0) {
          atomicAdd(&rstat[row].x, s);
          atomicAdd(&rstat[row].y, s2);
        }
      }
    }
  }
}

// rstat: (sum, sum^2) -> (a=rstd, c=-mu*rstd)
__global__ void k_rowfin(float2* rstat, int n) {
  int i = blockIdx.x * 256 + threadIdx.x;
  if (i < n) {
    float2 st = rstat[i];
    float mu = st.x * (1.f / 512.f);
    float var = st.y * (1.f / 512.f) - mu * mu;
    float rs = rsqrtf(var + 1e-5f);
    rstat[i] = make_float2(rs, -mu * rs);
  }
}

// ------------------------------- GEMM2 -------------------------------------
// h[M,256] += LN_relu(t1)[M,512] @ W2 + b2 (+ vn[batch[row]] if VN).
// loadtile = PURE raw loads (prefetch overlaps MFMA); the LN+ReLU transform
// runs in writetile, post-compute, exactly where the vmcnt drain sits.
template <int VN>
__global__ __launch_bounds__(256, 2) void k_gemm2(
    const _Float16* __restrict__ A, const _Float16* __restrict__ BT,
    const float* __restrict__ bias, const float2* __restrict__ rstat,
    const float* __restrict__ lg, const float* __restrict__ lb,
    const float* __restrict__ vn, const int* __restrict__ batch,
    float* __restrict__ outf, int M) {
  constexpr int K = 512, NN = 256;
  __shared__ _Float16 ldsA[128 * 64];
  __shared__ _Float16 ldsB[128 * 64];
  __shared__ float sg[512];
  __shared__ float sbt[512];
  const int tid = threadIdx.x;
  sg[tid] = lg[tid];
  sg[tid + 256] = lg[tid + 256];
  sbt[tid] = lb[tid];
  sbt[tid + 256] = lb[tid + 256];
  __syncthreads();

  const int lane = tid & 63;
  const int wv = tid >> 6;
  const int m0 = blockIdx.x * 128;
  const int n0 = blockIdx.y * 128;
  const int wm = (wv >> 1) * 64;
  const int wn = (wv & 1) * 64;
  const int q = lane >> 4;
  const int l16 = lane & 15;
  floatx4 acc[4][4] = {};

  size_t offA[4], offB[4];
  int ldsOff[4], gcol[4];
  float aco[4], cco[4];
#pragma unroll
  for (int i = 0; i < 4; ++i) {
    int p = (i * 4 + wv) * 64 + lane;
    int r = p >> 3;
    int s = p & 7;
    int g = s ^ (r & 7);
    int rowA = m0 + r;
    rowA = rowA < M ? rowA : (M - 1);
    offA[i] = (size_t)rowA * K + g * 8;
    offB[i] = (size_t)(n0 + r) * K + g * 8;
    ldsOff[i] = p * 8;
    gcol[i] = g * 8;
    float2 st = rstat[rowA];  // row fixed across k-tiles
    aco[i] = st.x;
    cco[i] = st.y;
  }
  half8_t ra[4], rb[4];
  auto loadtile = [&](int kt) {  // raw loads ONLY -- no dependent VALU here
#pragma unroll
    for (int i = 0; i < 4; ++i) {
      ra[i] = *(const half8_t*)(A + offA[i] + kt);
      rb[i] = *(const half8_t*)(BT + offB[i] + kt);
    }
  };
  auto writetile = [&](int kt) {  // LN+ReLU applied here (post-compute)
#pragma unroll
    for (int i = 0; i < 4; ++i) {
      int c0 = kt + gcol[i];
      half8_t ya;
#pragma unroll
      for (int j = 0; j < 8; ++j) {
        float e = fmaf((float)ra[i][j], aco[i], cco[i]);
        float y = fmaf(e, sg[c0 + j], sbt[c0 + j]);
        ya[j] = (_Float16)fmaxf(y, 0.f);
      }
      *(half8_t*)(ldsA + ldsOff[i]) = ya;
      *(half8_t*)(ldsB + ldsOff[i]) = rb[i];
    }
  };

  loadtile(0);
  writetile(0);
  for (int kt = 0; kt < K; kt += 64) {
    __syncthreads();
    if (kt + 64 < K) loadtile(kt + 64);
#pragma unroll
    for (int kk = 0; kk < 2; ++kk) {
      half8_t af[4], bf[4];
      const int c8 = kk * 4 + q;
#pragma unroll
      for (int rt = 0; rt < 4; ++rt) {
        int r = wm + rt * 16 + l16;
        af[rt] = *(const half8_t*)(ldsA + (size_t)(r * 8 + (c8 ^ (r & 7))) * 8);
      }
#pragma unroll
      for (int ct = 0; ct < 4; ++ct) {
        int n = wn + ct * 16 + l16;
        bf[ct] = *(const half8_t*)(ldsB + (size_t)(n * 8 + (c8 ^ (n & 7))) * 8);
      }
#pragma unroll
      for (int rt = 0; rt < 4; ++rt)
#pragma unroll
        for (int ct = 0; ct < 4; ++ct)
          acc[rt][ct] = __builtin_amdgcn_mfma_f32_16x16x32_f16(af[rt], bf[ct], acc[rt][ct], 0, 0, 0);
    }
    __syncthreads();
    if (kt + 64 < K) writetile(kt + 64);
  }

#pragma unroll
  for (int rt = 0; rt < 4; ++rt) {
#pragma unroll
    for (int rr = 0; rr < 4; ++rr) {
      int row = m0 + wm + rt * 16 + q * 4 + rr;
      if (row < M) {
        int bb = 0;
        if constexpr (VN) bb = batch[row];
#pragma unroll
        for (int ct = 0; ct < 4; ++ct) {
          int col = n0 + wn + ct * 16 + l16;
          float v = acc[rt][ct][rr] + bias[col];
          if constexpr (VN) v += vn[(size_t)bb * 256 + col];
          outf[(size_t)row * NN + col] += v;
        }
      }
    }
  }
}

// ---------------------- weight transpose+convert to f16 --------------------
__global__ __launch_bounds__(256) void k_wcvt(
    const float* __restrict__ W, _Float16* __restrict__ WT, int K_, int N_) {
  int idx = blockIdx.x * 256 + threadIdx.x;
  if (idx < K_ * N_) {
    int k = idx / N_, n = idx - k * N_;
    WT[(size_t)n * K_ + k] = (_Float16)W[idx];
  }
}

// --------------------------- virtual node sum ------------------------------
__global__ __launch_bounds__(256) void k_vnsum(
    const float* __restrict__ h, float* __restrict__ vn,
    const int* __restrict__ bptr, const float* __restrict__ invc) {
  int b = blockIdx.x, j = threadIdx.x;
  int n0 = bptr[b], n1 = bptr[b + 1];
  float acc = 0.f;
  for (int n = n0; n < n1; ++n) acc += h[(size_t)n * 256 + j];
  vn[(size_t)b * 256 + j] += acc * invc[b];
}

__global__ __launch_bounds__(256) void k_pool_f16(
    const _Float16* __restrict__ hnf, const int* __restrict__ bptr,
    const float* __restrict__ invc, float* __restrict__ out) {
  int b = blockIdx.x, j = threadIdx.x;
  int n0 = bptr[b], n1 = bptr[b + 1];
  float acc = 0.f;
  for (int n = n0; n < n1; ++n) acc += (float)hnf[(size_t)n * 256 + j];
  out[(size_t)b * 256 + j] = acc * invc[b];
}

// ---------------------------------------------------------------------------
extern "C" void kernel_launch(void* const* d_in, const int* in_sizes, int n_in,
                              void* d_out, int out_size, void* d_ws, size_t ws_size,
                              hipStream_t stream) {
  const float* x      = (const float*)d_in[0];
  const int*   ei     = (const int*)d_in[1];
  const float* eattr  = (const float*)d_in[2];
  const int*   batch  = (const int*)d_in[3];
  const float* nodeW  = (const float*)d_in[4];
  const float* nodeB  = (const float*)d_in[5];
  const float* edgeW  = (const float*)d_in[6];
  const float* edgeB  = (const float*)d_in[7];
  const float* vnemb  = (const float*)d_in[8];
  const float* lng    = (const float*)d_in[9];
  const float* lnb    = (const float*)d_in[10];
  const float* tparam = (const float*)d_in[11];
  const float* W1     = (const float*)d_in[12];
  const float* b1     = (const float*)d_in[13];
  const float* mlng   = (const float*)d_in[14];
  const float* mlnb   = (const float*)d_in[15];
  const float* W2     = (const float*)d_in[16];
  const float* b2     = (const float*)d_in[17];
  float* out = (float*)d_out;

  const int N = in_sizes[3];         // 100000
  const int E = in_sizes[1] / 2;     // 200000
  const int B = out_size / 256;      // 2048

  char* p = (char*)d_ws;
  auto take = [&](size_t bytes) -> char* {
    char* r = p;
    p += (bytes + 255) & ~(size_t)255;
    return r;
  };
  float*     h   = (float*)take((size_t)N * 256 * 4);
  _Float16*  t1  = (_Float16*)take((size_t)N * 512 * 2);  // GEMM1 out [N,512]
  _Float16*  hn  = t1;                 // [N,256] f16 aliases t1 (disjoint lifetimes)
  _Float16*  agg = (_Float16*)take((size_t)N * 256 * 2);
  _Float16*  W1T = (_Float16*)take((size_t)3 * 512 * 256 * 2);
  _Float16*  W2T = (_Float16*)take((size_t)3 * 256 * 512 * 2);
  float2*    rstat = (float2*)take((size_t)N * 8);
  float*     vn  = (float*)take((size_t)B * 256 * 4);
  int*       counts = (int*)take((size_t)B * 4);
  int*       bptr   = (int*)take((size_t)(B + 1) * 4);
  float*     invc   = (float*)take((size_t)B * 4);
  int*       deg    = (int*)take((size_t)N * 4);
  int*       indptr = (int*)take((size_t)(N + 1) * 4);
  int*       cursor = (int*)take((size_t)N * 4);
  int*       csr_src = (int*)take((size_t)E * 4);
  int*       csr_eid = (int*)take((size_t)E * 4);
  int*       bsum    = (int*)take(512 * 4);
  (void)ws_size; (void)n_in;

  hipMemsetAsync(counts, 0, (size_t)B * 4, stream);
  hipMemsetAsync(deg, 0, (size_t)N * 4, stream);

  k_node_enc<<<(N + 7) / 8, 256, 0, stream>>>(x, nodeW, nodeB, h, N);

  const int nbB = (B + 1023) / 1024;
  k_count<<<(N + 255) / 256, 256, 0, stream>>>(batch, counts, N);
  k_scan1<<<nbB, 256, 0, stream>>>(counts, bptr + 1, bsum, B);
  k_scan2<<<1, 64, 0, stream>>>(bsum, nbB, bptr);
  k_scan3<<<nbB, 256, 0, stream>>>(bptr + 1, bsum, B);
  k_invc<<<(B + 255) / 256, 256, 0, stream>>>(counts, invc, B);

  const int nbN = (N + 1023) / 1024;
  k_deg<<<(E + 255) / 256, 256, 0, stream>>>(ei, deg, E);
  k_scan1<<<nbN, 256, 0, stream>>>(deg, indptr + 1, bsum, N);
  k_scan2<<<1, 64, 0, stream>>>(bsum, nbN, indptr);
  k_scan3<<<nbN, 256, 0, stream>>>(indptr + 1, bsum, N);
  k_copy<<<(N + 255) / 256, 256, 0, stream>>>(indptr, cursor, N);
  k_csrfill<<<(E + 255) / 256, 256, 0, stream>>>(ei, cursor, csr_src, csr_eid, E);

  for (int l = 0; l < 3; ++l) {
    k_wcvt<<<512, 256, 0, stream>>>(W1 + (size_t)l * 256 * 512, W1T + (size_t)l * 512 * 256, 256, 512);
    k_wcvt<<<512, 256, 0, stream>>>(W2 + (size_t)l * 512 * 256, W2T + (size_t)l * 256 * 512, 512, 256);
  }
  k_vninit<<<B, 256, 0, stream>>>(vnemb, vn);

  const int lnGrid = (N + 3) / 4;
  const int mTiles = (N + 127) / 128;
  for (int l = 1; l <= 3; ++l) {
    if (l == 1)
      k_ln256<0><<<lnGrid, 256, 0, stream>>>(
          h, nullptr, nullptr, lng + (size_t)l * 256, lnb + (size_t)l * 256, hn, N);
    else
      k_ln256<1><<<lnGrid, 256, 0, stream>>>(
          h, vn, batch, lng + (size_t)l * 256, lnb + (size_t)l * 256, hn, N);
    k_aggregate<<<lnGrid, 256, 0, stream>>>(hn, eattr, edgeW, edgeB, indptr, csr_src, csr_eid,
                                            tparam + (l - 1), agg, N);
    hipMemsetAsync(rstat, 0, (size_t)N * 8, stream);
    k_gemm1<<<dim3(mTiles, 4), 256, 0, stream>>>(
        agg, W1T + (size_t)(l - 1) * 512 * 256, b1 + (size_t)(l - 1) * 512, t1, rstat, N);
    k_rowfin<<<(N + 255) / 256, 256, 0, stream>>>(rstat, N);
    if (l == 1)
      k_gemm2<0><<<dim3(mTiles, 2), 256, 0, stream>>>(
          t1, W2T + (size_t)(l - 1) * 256 * 512, b2 + (size_t)(l - 1) * 256, rstat,
          mlng + (size_t)(l - 1) * 512, mlnb + (size_t)(l - 1) * 512, nullptr, nullptr, h, N);
    else
      k_gemm2<1><<<dim3(mTiles, 2), 256, 0, stream>>>(
          t1, W2T + (size_t)(l - 1) * 256 * 512, b2 + (size_t)(l - 1) * 256, rstat,
          mlng + (size_t)(l - 1) * 512, mlnb + (size_t)(l - 1) * 512, vn, batch, h, N);
    k_vnsum<<<B, 256, 0, stream>>>(h, vn, bptr, invc);
  }

  // final: logical h = h + vn3[batch], LN -> f16, mean pool
  k_ln256<1><<<lnGrid, 256, 0, stream>>>(h, vn, batch, lng, lnb, hn, N);
  k_pool_f16<<<B, 256, 0, stream>>>(hn, bptr, invc, out);
}

// Round 6
// 992.561 us; speedup vs baseline: 1.1728x; 1.0484x over previous
//
#include <hip/hip_runtime.h>
#include <cstdint>
#include <cstddef>

// ---------------------------------------------------------------------------
// VirtualNodeGNN: 3x GENConv(softmax aggr) + virtual node + mean pool.
// R6 changes vs R5 (1040 us):
//   - GEMM k-loops: prefetch DEPTH 2 (ping-pong register buffers, unrolled
//     k-loop). R5's depth-1 left loads in flight for only ~1 MFMA block
//     (~400cyc) vs ~900cyc HBM latency -> per-iter vmcnt stall. Depth 2
//     covers it.
//   - h residual stream f32 -> f16 (LN makes h scale-invariant; rel err 5e-4):
//     saves ~460 MB/call across node_enc/ln256/gemm2-RMW/vnsum/final-LN.
// ---------------------------------------------------------------------------

typedef _Float16 half8_t __attribute__((ext_vector_type(8)));
typedef _Float16 half4_t __attribute__((ext_vector_type(4)));
typedef float    floatx4 __attribute__((ext_vector_type(4)));

#define DEVINL __device__ __forceinline__

DEVINL float wave_sum(float v) {
#pragma unroll
  for (int m = 32; m; m >>= 1) v += __shfl_xor(v, m, 64);
  return v;
}

// ------------------------------- node encoder ------------------------------
__global__ __launch_bounds__(256) void k_node_enc(
    const float* __restrict__ x, const float* __restrict__ W,
    const float* __restrict__ bias, _Float16* __restrict__ h, int Nr) {
  __shared__ float sW[9 * 256];
  __shared__ float sb[256];
  __shared__ float sx[72];
  const int j = threadIdx.x;
#pragma unroll
  for (int k = 0; k < 9; ++k) sW[k * 256 + j] = W[k * 256 + j];
  sb[j] = bias[j];
  const int row0 = blockIdx.x * 8;
  if (j < 72) {
    int p = row0 * 9 + j;
    sx[j] = (p < Nr * 9) ? x[p] : 0.f;
  }
  __syncthreads();
  for (int r = 0; r < 8; ++r) {
    int row = row0 + r;
    if (row >= Nr) break;
    float acc = sb[j];
#pragma unroll
    for (int k = 0; k < 9; ++k) acc = fmaf(sx[r * 9 + k], sW[k * 256 + j], acc);
    h[(size_t)row * 256 + j] = (_Float16)acc;
  }
}

// ------------------------- counting / scan / CSR ---------------------------
__global__ void k_count(const int* __restrict__ batch, int* __restrict__ counts, int n) {
  int i = blockIdx.x * 256 + threadIdx.x;
  if (i < n) atomicAdd(&counts[batch[i]], 1);
}

__global__ void k_deg(const int* __restrict__ ei, int* __restrict__ deg, int E_) {
  int e = blockIdx.x * 256 + threadIdx.x;
  if (e < E_) atomicAdd(&deg[ei[E_ + e]], 1);  // row 1 of edge_index = dst
}

__global__ __launch_bounds__(256) void k_scan1(
    const int* __restrict__ in, int* __restrict__ out1, int* __restrict__ bsum, int n) {
  __shared__ int tmp[256];
  const int t = threadIdx.x;
  const int base = blockIdx.x * 1024;
  int v[4];
  int run = 0;
#pragma unroll
  for (int i = 0; i < 4; ++i) {
    int p = base + t * 4 + i;
    int xv = (p < n) ? in[p] : 0;
    run += xv;
    v[i] = run;
  }
  tmp[t] = run;
  __syncthreads();
  for (int off = 1; off < 256; off <<= 1) {
    int u = (t >= off) ? tmp[t - off] : 0;
    __syncthreads();
    tmp[t] += u;
    __syncthreads();
  }
  int excl = tmp[t] - run;
#pragma unroll
  for (int i = 0; i < 4; ++i) {
    int p = base + t * 4 + i;
    if (p < n) out1[p] = v[i] + excl;
  }
  if (t == 255) bsum[blockIdx.x] = tmp[255];
}

__global__ void k_scan2(int* bsum, int nb, int* ptr0) {
  if (threadIdx.x == 0 && blockIdx.x == 0) {
    int run = 0;
    for (int i = 0; i < nb; ++i) { int xv = bsum[i]; bsum[i] = run; run += xv; }
    ptr0[0] = 0;
  }
}

__global__ __launch_bounds__(256) void k_scan3(int* out1, const int* __restrict__ bsum, int n) {
  int add = bsum[blockIdx.x];
  int p0 = blockIdx.x * 1024 + threadIdx.x * 4;
#pragma unroll
  for (int i = 0; i < 4; ++i) {
    int p = p0 + i;
    if (p < n) out1[p] += add;
  }
}

__global__ void k_copy(const int* __restrict__ a, int* __restrict__ b, int n) {
  int i = blockIdx.x * 256 + threadIdx.x;
  if (i < n) b[i] = a[i];
}

__global__ void k_csrfill(const int* __restrict__ ei, int* __restrict__ cursor,
                          int* __restrict__ csr_src, int* __restrict__ csr_eid, int E_) {
  int e = blockIdx.x * 256 + threadIdx.x;
  if (e < E_) {
    int d = ei[E_ + e];
    int pos = atomicAdd(&cursor[d], 1);
    csr_src[pos] = ei[e];
    csr_eid[pos] = e;
  }
}

__global__ void k_invc(const int* __restrict__ counts, float* __restrict__ invc, int Bn) {
  int i = blockIdx.x * 256 + threadIdx.x;
  if (i < Bn) {
    int c = counts[i];
    invc[i] = 1.f / (float)(c > 1 ? c : 1);
  }
}

__global__ void k_vninit(const float* __restrict__ emb, float* __restrict__ vn) {
  vn[(size_t)blockIdx.x * 256 + threadIdx.x] = emb[threadIdx.x];
}

// ------------------------------ LayerNorm 256 ------------------------------
// wave-per-row; h is f16. VN: logical input = h + vn[batch[row]].
template <int VN>
__global__ __launch_bounds__(256) void k_ln256(
    const _Float16* __restrict__ h, const float* __restrict__ vn,
    const int* __restrict__ batch, const float* __restrict__ g,
    const float* __restrict__ b, _Float16* __restrict__ out, int Nr) {
  int row = blockIdx.x * 4 + (threadIdx.x >> 6);
  if (row >= Nr) return;
  int lane = threadIdx.x & 63;
  half4_t xh = *(const half4_t*)(h + (size_t)row * 256 + lane * 4);
  float4 xv = {(float)xh[0], (float)xh[1], (float)xh[2], (float)xh[3]};
  if constexpr (VN) {
    int bb = batch[row];
    float4 vv = *(const float4*)(vn + (size_t)bb * 256 + lane * 4);
    xv.x += vv.x; xv.y += vv.y; xv.z += vv.z; xv.w += vv.w;
  }
  float s = wave_sum(xv.x + xv.y + xv.z + xv.w);
  float mu = s * (1.f / 256.f);
  float d0 = xv.x - mu, d1 = xv.y - mu, d2 = xv.z - mu, d3 = xv.w - mu;
  float v = wave_sum(d0 * d0 + d1 * d1 + d2 * d2 + d3 * d3);
  float rstd = rsqrtf(v * (1.f / 256.f) + 1e-5f);
  float4 gv = *(const float4*)(g + lane * 4);
  float4 bv = *(const float4*)(b + lane * 4);
  half4_t o;
  o[0] = (_Float16)fmaxf(d0 * rstd * gv.x + bv.x, 0.f);
  o[1] = (_Float16)fmaxf(d1 * rstd * gv.y + bv.y, 0.f);
  o[2] = (_Float16)fmaxf(d2 * rstd * gv.z + bv.z, 0.f);
  o[3] = (_Float16)fmaxf(d3 * rstd * gv.w + bv.w, 0.f);
  *(half4_t*)(out + (size_t)row * 256 + lane * 4) = o;
}

// --------------------------- softmax aggregation ---------------------------
__global__ __launch_bounds__(256) void k_aggregate(
    const _Float16* __restrict__ hn, const float* __restrict__ eattr,
    const float* __restrict__ edgeW, const float* __restrict__ edgeB,
    const int* __restrict__ indptr, const int* __restrict__ csr_src,
    const int* __restrict__ csr_eid, const float* __restrict__ tptr,
    _Float16* __restrict__ agg, int Nr) {
  __shared__ float sW[4 * 256];  // [k*256+j] k=0..2 weights, k=3 bias
  const int tj = threadIdx.x;
  sW[tj] = edgeW[tj];
  sW[256 + tj] = edgeW[256 + tj];
  sW[512 + tj] = edgeW[512 + tj];
  sW[768 + tj] = edgeB[tj];
  __syncthreads();

  int node = blockIdx.x * 4 + (threadIdx.x >> 6);
  if (node >= Nr) return;
  int lane = threadIdx.x & 63;
  float tval = tptr[0];
  int e0 = indptr[node], e1 = indptr[node + 1];
  float M[4], D[4], Nu[4];
#pragma unroll
  for (int i = 0; i < 4; ++i) { M[i] = -1e38f; D[i] = 0.f; Nu[i] = 0.f; }
  for (int s = e0; s < e1; ++s) {
    int srcn = csr_src[s];
    int eid = csr_eid[s];
    float ex0 = eattr[(size_t)eid * 3 + 0];
    float ex1 = eattr[(size_t)eid * 3 + 1];
    float ex2 = eattr[(size_t)eid * 3 + 2];
    half4_t hv = *(const half4_t*)(hn + (size_t)srcn * 256 + lane * 4);
#pragma unroll
    for (int i = 0; i < 4; ++i) {
      int j = lane * 4 + i;
      float eaj = fmaf(ex0, sW[j], fmaf(ex1, sW[256 + j], fmaf(ex2, sW[512 + j], sW[768 + j])));
      float msg = fmaxf((float)hv[i] + eaj, 0.f) + 1e-7f;
      float sc = msg * tval;
      float nM = fmaxf(M[i], sc);
      float sOld = __expf(M[i] - nM);
      float pr = __expf(sc - nM);
      D[i] = D[i] * sOld + pr;
      Nu[i] = Nu[i] * sOld + pr * msg;
      M[i] = nM;
    }
  }
  half4_t hs = *(const half4_t*)(hn + (size_t)node * 256 + lane * 4);
  half4_t res;
#pragma unroll
  for (int i = 0; i < 4; ++i)
    res[i] = (_Float16)(Nu[i] / (D[i] + 1e-16f) + (float)hs[i]);
  *(half4_t*)(agg + (size_t)node * 256 + lane * 4) = res;
}

// ------------------------------- GEMM1 -------------------------------------
// t1[M,512] = agg[M,256] @ W1 + b1 (f16 out), plus per-row (sum,sum^2) into
// rstat via 16-lane shfl-reduce + atomics. Prefetch depth 2 (ping-pong regs).
__global__ __launch_bounds__(256, 2) void k_gemm1(
    const _Float16* __restrict__ A, const _Float16* __restrict__ BT,
    const float* __restrict__ bias, _Float16* __restrict__ outh,
    float2* __restrict__ rstat, int M) {
  constexpr int K = 256, NN = 512, NT = K / 64;
  __shared__ _Float16 ldsA[128 * 64];
  __shared__ _Float16 ldsB[128 * 64];
  const int lane = threadIdx.x & 63;
  const int wv = threadIdx.x >> 6;
  const int m0 = blockIdx.x * 128;
  const int n0 = blockIdx.y * 128;
  const int wm = (wv >> 1) * 64;
  const int wn = (wv & 1) * 64;
  const int q = lane >> 4;
  const int l16 = lane & 15;
  floatx4 acc[4][4] = {};

  size_t offA[4], offB[4];
  int ldsOff[4];
#pragma unroll
  for (int i = 0; i < 4; ++i) {
    int p = (i * 4 + wv) * 64 + lane;
    int r = p >> 3;
    int s = p & 7;
    int g = s ^ (r & 7);
    int rowA = m0 + r;
    rowA = rowA < M ? rowA : (M - 1);
    offA[i] = (size_t)rowA * K + g * 8;
    offB[i] = (size_t)(n0 + r) * K + g * 8;
    ldsOff[i] = p * 8;
  }
  half8_t bufA[2][4], bufB[2][4];
  auto loadtile = [&](int kt, int bsel) {
#pragma unroll
    for (int i = 0; i < 4; ++i) {
      bufA[bsel][i] = *(const half8_t*)(A + offA[i] + kt);
      bufB[bsel][i] = *(const half8_t*)(BT + offB[i] + kt);
    }
  };
  auto writetile = [&](int bsel) {
#pragma unroll
    for (int i = 0; i < 4; ++i) {
      *(half8_t*)(ldsA + ldsOff[i]) = bufA[bsel][i];
      *(half8_t*)(ldsB + ldsOff[i]) = bufB[bsel][i];
    }
  };

  loadtile(0, 0);
  loadtile(64, 1);
  writetile(0);
#pragma unroll
  for (int t = 0; t < NT; ++t) {
    __syncthreads();
    if (t + 2 < NT) loadtile((t + 2) * 64, t & 1);
#pragma unroll
    for (int kk = 0; kk < 2; ++kk) {
      half8_t af[4], bf[4];
      const int c8 = kk * 4 + q;
#pragma unroll
      for (int rt = 0; rt < 4; ++rt) {
        int r = wm + rt * 16 + l16;
        af[rt] = *(const half8_t*)(ldsA + (size_t)(r * 8 + (c8 ^ (r & 7))) * 8);
      }
#pragma unroll
      for (int ct = 0; ct < 4; ++ct) {
        int n = wn + ct * 16 + l16;
        bf[ct] = *(const half8_t*)(ldsB + (size_t)(n * 8 + (c8 ^ (n & 7))) * 8);
      }
#pragma unroll
      for (int rt = 0; rt < 4; ++rt)
#pragma unroll
        for (int ct = 0; ct < 4; ++ct)
          acc[rt][ct] = __builtin_amdgcn_mfma_f32_16x16x32_f16(af[rt], bf[ct], acc[rt][ct], 0, 0, 0);
    }
    __syncthreads();
    if (t + 1 < NT) writetile((t + 1) & 1);
  }

#pragma unroll
  for (int rt = 0; rt < 4; ++rt) {
#pragma unroll
    for (int rr = 0; rr < 4; ++rr) {
      int row = m0 + wm + rt * 16 + q * 4 + rr;  // C/D: col=lane&15, row=q*4+reg
      float vv[4];
      float s = 0.f, s2 = 0.f;
#pragma unroll
      for (int ct = 0; ct < 4; ++ct) {
        int col = n0 + wn + ct * 16 + l16;
        float v = acc[rt][ct][rr] + bias[col];
        vv[ct] = v;
        s += v;
        s2 += v * v;
      }
#pragma unroll
      for (int m = 1; m < 16; m <<= 1) {
        s += __shfl_xor(s, m, 64);
        s2 += __shfl_xor(s2, m, 64);
      }
      if (row < M) {
#pragma unroll
        for (int ct = 0; ct < 4; ++ct) {
          int col = n0 + wn + ct * 16 + l16;
          outh[(size_t)row * NN + col] = (_Float16)vv[ct];
        }
        if (l16 == 0) {
          atomicAdd(&rstat[row].x, s);
          atomicAdd(&rstat[row].y, s2);
        }
      }
    }
  }
}

// rstat: (sum, sum^2) -> (a=rstd, c=-mu*rstd)
__global__ void k_rowfin(float2* rstat, int n) {
  int i = blockIdx.x * 256 + threadIdx.x;
  if (i < n) {
    float2 st = rstat[i];
    float mu = st.x * (1.f / 512.f);
    float var = st.y * (1.f / 512.f) - mu * mu;
    float rs = rsqrtf(var + 1e-5f);
    rstat[i] = make_float2(rs, -mu * rs);
  }
}

// ------------------------------- GEMM2 -------------------------------------
// h[M,256] (f16) += LN_relu(t1)[M,512] @ W2 + b2 (+ vn[batch[row]] if VN).
// loadtile = pure raw loads, depth-2 ping-pong prefetch; LN+ReLU transform in
// writetile (post-compute, at the natural vmcnt drain point).
template <int VN>
__global__ __launch_bounds__(256, 2) void k_gemm2(
    const _Float16* __restrict__ A, const _Float16* __restrict__ BT,
    const float* __restrict__ bias, const float2* __restrict__ rstat,
    const float* __restrict__ lg, const float* __restrict__ lb,
    const float* __restrict__ vn, const int* __restrict__ batch,
    _Float16* __restrict__ outf, int M) {
  constexpr int K = 512, NN = 256, NT = K / 64;
  __shared__ _Float16 ldsA[128 * 64];
  __shared__ _Float16 ldsB[128 * 64];
  __shared__ float sg[512];
  __shared__ float sbt[512];
  const int tid = threadIdx.x;
  sg[tid] = lg[tid];
  sg[tid + 256] = lg[tid + 256];
  sbt[tid] = lb[tid];
  sbt[tid + 256] = lb[tid + 256];
  __syncthreads();

  const int lane = tid & 63;
  const int wv = tid >> 6;
  const int m0 = blockIdx.x * 128;
  const int n0 = blockIdx.y * 128;
  const int wm = (wv >> 1) * 64;
  const int wn = (wv & 1) * 64;
  const int q = lane >> 4;
  const int l16 = lane & 15;
  floatx4 acc[4][4] = {};

  size_t offA[4], offB[4];
  int ldsOff[4], gcol[4];
  float aco[4], cco[4];
#pragma unroll
  for (int i = 0; i < 4; ++i) {
    int p = (i * 4 + wv) * 64 + lane;
    int r = p >> 3;
    int s = p & 7;
    int g = s ^ (r & 7);
    int rowA = m0 + r;
    rowA = rowA < M ? rowA : (M - 1);
    offA[i] = (size_t)rowA * K + g * 8;
    offB[i] = (size_t)(n0 + r) * K + g * 8;
    ldsOff[i] = p * 8;
    gcol[i] = g * 8;
    float2 st = rstat[rowA];  // row fixed across k-tiles
    aco[i] = st.x;
    cco[i] = st.y;
  }
  half8_t bufA[2][4], bufB[2][4];
  auto loadtile = [&](int kt, int bsel) {  // raw loads ONLY
#pragma unroll
    for (int i = 0; i < 4; ++i) {
      bufA[bsel][i] = *(const half8_t*)(A + offA[i] + kt);
      bufB[bsel][i] = *(const half8_t*)(BT + offB[i] + kt);
    }
  };
  auto writetile = [&](int kt, int bsel) {  // LN+ReLU applied here
#pragma unroll
    for (int i = 0; i < 4; ++i) {
      int c0 = kt + gcol[i];
      half8_t ya;
#pragma unroll
      for (int j = 0; j < 8; ++j) {
        float e = fmaf((float)bufA[bsel][i][j], aco[i], cco[i]);
        float y = fmaf(e, sg[c0 + j], sbt[c0 + j]);
        ya[j] = (_Float16)fmaxf(y, 0.f);
      }
      *(half8_t*)(ldsA + ldsOff[i]) = ya;
      *(half8_t*)(ldsB + ldsOff[i]) = bufB[bsel][i];
    }
  };

  loadtile(0, 0);
  loadtile(64, 1);
  writetile(0, 0);
#pragma unroll
  for (int t = 0; t < NT; ++t) {
    __syncthreads();
    if (t + 2 < NT) loadtile((t + 2) * 64, t & 1);
#pragma unroll
    for (int kk = 0; kk < 2; ++kk) {
      half8_t af[4], bf[4];
      const int c8 = kk * 4 + q;
#pragma unroll
      for (int rt = 0; rt < 4; ++rt) {
        int r = wm + rt * 16 + l16;
        af[rt] = *(const half8_t*)(ldsA + (size_t)(r * 8 + (c8 ^ (r & 7))) * 8);
      }
#pragma unroll
      for (int ct = 0; ct < 4; ++ct) {
        int n = wn + ct * 16 + l16;
        bf[ct] = *(const half8_t*)(ldsB + (size_t)(n * 8 + (c8 ^ (n & 7))) * 8);
      }
#pragma unroll
      for (int rt = 0; rt < 4; ++rt)
#pragma unroll
        for (int ct = 0; ct < 4; ++ct)
          acc[rt][ct] = __builtin_amdgcn_mfma_f32_16x16x32_f16(af[rt], bf[ct], acc[rt][ct], 0, 0, 0);
    }
    __syncthreads();
    if (t + 1 < NT) writetile((t + 1) * 64, (t + 1) & 1);
  }

#pragma unroll
  for (int rt = 0; rt < 4; ++rt) {
#pragma unroll
    for (int rr = 0; rr < 4; ++rr) {
      int row = m0 + wm + rt * 16 + q * 4 + rr;
      if (row < M) {
        int bb = 0;
        if constexpr (VN) bb = batch[row];
#pragma unroll
        for (int ct = 0; ct < 4; ++ct) {
          int col = n0 + wn + ct * 16 + l16;
          float v = acc[rt][ct][rr] + bias[col];
          if constexpr (VN) v += vn[(size_t)bb * 256 + col];
          size_t idx = (size_t)row * NN + col;
          outf[idx] = (_Float16)((float)outf[idx] + v);
        }
      }
    }
  }
}

// ---------------------- weight transpose+convert to f16 --------------------
__global__ __launch_bounds__(256) void k_wcvt(
    const float* __restrict__ W, _Float16* __restrict__ WT, int K_, int N_) {
  int idx = blockIdx.x * 256 + threadIdx.x;
  if (idx < K_ * N_) {
    int k = idx / N_, n = idx - k * N_;
    WT[(size_t)n * K_ + k] = (_Float16)W[idx];
  }
}

// --------------------------- virtual node sum ------------------------------
__global__ __launch_bounds__(256) void k_vnsum(
    const _Float16* __restrict__ h, float* __restrict__ vn,
    const int* __restrict__ bptr, const float* __restrict__ invc) {
  int b = blockIdx.x, j = threadIdx.x;
  int n0 = bptr[b], n1 = bptr[b + 1];
  float acc = 0.f;
  for (int n = n0; n < n1; ++n) acc += (float)h[(size_t)n * 256 + j];
  vn[(size_t)b * 256 + j] += acc * invc[b];
}

__global__ __launch_bounds__(256) void k_pool_f16(
    const _Float16* __restrict__ hnf, const int* __restrict__ bptr,
    const float* __restrict__ invc, float* __restrict__ out) {
  int b = blockIdx.x, j = threadIdx.x;
  int n0 = bptr[b], n1 = bptr[b + 1];
  float acc = 0.f;
  for (int n = n0; n < n1; ++n) acc += (float)hnf[(size_t)n * 256 + j];
  out[(size_t)b * 256 + j] = acc * invc[b];
}

// ---------------------------------------------------------------------------
extern "C" void kernel_launch(void* const* d_in, const int* in_sizes, int n_in,
                              void* d_out, int out_size, void* d_ws, size_t ws_size,
                              hipStream_t stream) {
  const float* x      = (const float*)d_in[0];
  const int*   ei     = (const int*)d_in[1];
  const float* eattr  = (const float*)d_in[2];
  const int*   batch  = (const int*)d_in[3];
  const float* nodeW  = (const float*)d_in[4];
  const float* nodeB  = (const float*)d_in[5];
  const float* edgeW  = (const float*)d_in[6];
  const float* edgeB  = (const float*)d_in[7];
  const float* vnemb  = (const float*)d_in[8];
  const float* lng    = (const float*)d_in[9];
  const float* lnb    = (const float*)d_in[10];
  const float* tparam = (const float*)d_in[11];
  const float* W1     = (const float*)d_in[12];
  const float* b1     = (const float*)d_in[13];
  const float* mlng   = (const float*)d_in[14];
  const float* mlnb   = (const float*)d_in[15];
  const float* W2     = (const float*)d_in[16];
  const float* b2     = (const float*)d_in[17];
  float* out = (float*)d_out;

  const int N = in_sizes[3];         // 100000
  const int E = in_sizes[1] / 2;     // 200000
  const int B = out_size / 256;      // 2048

  char* p = (char*)d_ws;
  auto take = [&](size_t bytes) -> char* {
    char* r = p;
    p += (bytes + 255) & ~(size_t)255;
    return r;
  };
  _Float16*  h   = (_Float16*)take((size_t)N * 256 * 2);  // f16 residual stream
  _Float16*  t1  = (_Float16*)take((size_t)N * 512 * 2);  // GEMM1 out [N,512]
  _Float16*  hn  = t1;                 // [N,256] f16 aliases t1 (disjoint lifetimes)
  _Float16*  agg = (_Float16*)take((size_t)N * 256 * 2);
  _Float16*  W1T = (_Float16*)take((size_t)3 * 512 * 256 * 2);
  _Float16*  W2T = (_Float16*)take((size_t)3 * 256 * 512 * 2);
  float2*    rstat = (float2*)take((size_t)N * 8);
  float*     vn  = (float*)take((size_t)B * 256 * 4);
  int*       counts = (int*)take((size_t)B * 4);
  int*       bptr   = (int*)take((size_t)(B + 1) * 4);
  float*     invc   = (float*)take((size_t)B * 4);
  int*       deg    = (int*)take((size_t)N * 4);
  int*       indptr = (int*)take((size_t)(N + 1) * 4);
  int*       cursor = (int*)take((size_t)N * 4);
  int*       csr_src = (int*)take((size_t)E * 4);
  int*       csr_eid = (int*)take((size_t)E * 4);
  int*       bsum    = (int*)take(512 * 4);
  (void)ws_size; (void)n_in;

  hipMemsetAsync(counts, 0, (size_t)B * 4, stream);
  hipMemsetAsync(deg, 0, (size_t)N * 4, stream);

  k_node_enc<<<(N + 7) / 8, 256, 0, stream>>>(x, nodeW, nodeB, h, N);

  const int nbB = (B + 1023) / 1024;
  k_count<<<(N + 255) / 256, 256, 0, stream>>>(batch, counts, N);
  k_scan1<<<nbB, 256, 0, stream>>>(counts, bptr + 1, bsum, B);
  k_scan2<<<1, 64, 0, stream>>>(bsum, nbB, bptr);
  k_scan3<<<nbB, 256, 0, stream>>>(bptr + 1, bsum, B);
  k_invc<<<(B + 255) / 256, 256, 0, stream>>>(counts, invc, B);

  const int nbN = (N + 1023) / 1024;
  k_deg<<<(E + 255) / 256, 256, 0, stream>>>(ei, deg, E);
  k_scan1<<<nbN, 256, 0, stream>>>(deg, indptr + 1, bsum, N);
  k_scan2<<<1, 64, 0, stream>>>(bsum, nbN, indptr);
  k_scan3<<<nbN, 256, 0, stream>>>(indptr + 1, bsum, N);
  k_copy<<<(N + 255) / 256, 256, 0, stream>>>(indptr, cursor, N);
  k_csrfill<<<(E + 255) / 256, 256, 0, stream>>>(ei, cursor, csr_src, csr_eid, E);

  for (int l = 0; l < 3; ++l) {
    k_wcvt<<<512, 256, 0, stream>>>(W1 + (size_t)l * 256 * 512, W1T + (size_t)l * 512 * 256, 256, 512);
    k_wcvt<<<512, 256, 0, stream>>>(W2 + (size_t)l * 512 * 256, W2T + (size_t)l * 256 * 512, 512, 256);
  }
  k_vninit<<<B, 256, 0, stream>>>(vnemb, vn);

  const int lnGrid = (N + 3) / 4;
  const int mTiles = (N + 127) / 128;
  for (int l = 1; l <= 3; ++l) {
    if (l == 1)
      k_ln256<0><<<lnGrid, 256, 0, stream>>>(
          h, nullptr, nullptr, lng + (size_t)l * 256, lnb + (size_t)l * 256, hn, N);
    else
      k_ln256<1><<<lnGrid, 256, 0, stream>>>(
          h, vn, batch, lng + (size_t)l * 256, lnb + (size_t)l * 256, hn, N);
    k_aggregate<<<lnGrid, 256, 0, stream>>>(hn, eattr, edgeW, edgeB, indptr, csr_src, csr_eid,
                                            tparam + (l - 1), agg, N);
    hipMemsetAsync(rstat, 0, (size_t)N * 8, stream);
    k_gemm1<<<dim3(mTiles, 4), 256, 0, stream>>>(
        agg, W1T + (size_t)(l - 1) * 512 * 256, b1 + (size_t)(l - 1) * 512, t1, rstat, N);
    k_rowfin<<<(N + 255) / 256, 256, 0, stream>>>(rstat, N);
    if (l == 1)
      k_gemm2<0><<<dim3(mTiles, 2), 256, 0, stream>>>(
          t1, W2T + (size_t)(l - 1) * 256 * 512, b2 + (size_t)(l - 1) * 256, rstat,
          mlng + (size_t)(l - 1) * 512, mlnb + (size_t)(l - 1) * 512, nullptr, nullptr, h, N);
    else
      k_gemm2<1><<<dim3(mTiles, 2), 256, 0, stream>>>(
          t1, W2T + (size_t)(l - 1) * 256 * 512, b2 + (size_t)(l - 1) * 256, rstat,
          mlng + (size_t)(l - 1) * 512, mlnb + (size_t)(l - 1) * 512, vn, batch, h, N);
    k_vnsum<<<B, 256, 0, stream>>>(h, vn, bptr, invc);
  }

  // final: logical h = h + vn3[batch], LN -> f16, mean pool
  k_ln256<1><<<lnGrid, 256, 0, stream>>>(h, vn, batch, lng, lnb, hn, N);
  k_pool_f16<<<B, 256, 0, stream>>>(hn, bptr, invc, out);
}